// Round 4
// baseline (311.052 us; speedup 1.0000x reference)
//
#include <hip/hip_runtime.h>
#include <hip/hip_bf16.h>

typedef short short8 __attribute__((ext_vector_type(8)));
typedef float f32x4 __attribute__((ext_vector_type(4)));

#define XS 136  // Xl row stride in bf16 elems: 128 + 8 pad (272 B/row -> 4-bank rotation)

static __device__ inline short f2bf(float f) {
    unsigned u = __float_as_uint(f);
    unsigned r = (u + 0x7fffu + ((u >> 16) & 1u)) >> 16;
    return (short)r;
}
static __device__ inline float bf2f(short s) {
    return __uint_as_float(((unsigned)(unsigned short)s) << 16);
}
// HW packed f32->bf16 RTNE (identical rounding to f2bf), 1 inst per 2 converts
static __device__ inline unsigned cvtpk(float lo, float hi) {
    unsigned r;
    asm("v_cvt_pk_bf16_f32 %0, %1, %2" : "=v"(r) : "v"(lo), "v"(hi));
    return r;
}

// Fused precompute.
// blocks [0,256):  U[b][j] = b1[j] + sum_d target[b][d] * (W1a[d][j] - W1c[d][j]) ; 8 b-rows/block
// blocks [256,512): build 128x256 bf16 fragment arrays in MFMA B-layout (16x16x32):
//   Wbc[k][n] = W1b[k][n] + W1c[k][n]   (item coefficient)
//   Wd [k][n] = W1d[k][n]               (dot coefficient, combined per-b in din_main)
// frag[((t*4+s)*64+l)*8+j] = src[s*32 + (l>>4)*8 + j][t*16 + (l&15)]
__global__ void precompute(const float* __restrict__ W1, const float* __restrict__ b1,
                           const float* __restrict__ target, short* __restrict__ Wbc,
                           short* __restrict__ Wd, float* __restrict__ U) {
    __shared__ float tl[1024];
    const int tid = threadIdx.x;
    if (blockIdx.x >= 256) {
        int idx = (blockIdx.x - 256) * 256 + tid;   // 65536 threads
        int half = idx >> 15;
        int i = idx & 32767;
        int j = i & 7;
        int l = (i >> 3) & 63;
        int s = (i >> 9) & 3;
        int t = i >> 11;
        int k = s * 32 + ((l >> 4) << 3) + j;
        int n = t * 16 + (l & 15);
        if (half == 0) Wbc[i] = f2bf(W1[(128 + k) * 256 + n] + W1[(256 + k) * 256 + n]);
        else           Wd[i]  = f2bf(W1[(384 + k) * 256 + n]);
        return;
    }
    const int b8 = blockIdx.x;
#pragma unroll
    for (int k = 0; k < 4; k++) tl[k * 256 + tid] = target[b8 * 1024 + k * 256 + tid];
    __syncthreads();
    float acc[8] = {0.f, 0.f, 0.f, 0.f, 0.f, 0.f, 0.f, 0.f};
#pragma unroll 8
    for (int d = 0; d < 128; ++d) {
        float wud = W1[d * 256 + tid] - W1[(256 + d) * 256 + tid];
#pragma unroll
        for (int r = 0; r < 8; r++) acc[r] += tl[r * 128 + d] * wud;
    }
    float bj = b1[tid];
#pragma unroll
    for (int r = 0; r < 8; r++) U[(b8 * 8 + r) * 256 + tid] = acc[r] + bj;
}

// Main fused kernel: one block per batch b; R4: 8 waves (512 thr), wave w owns n-tiles
// {2w, 2w+1}. Halves per-wave setup chain (8 frag builds vs 16) and per-wave bfrag
// VGPRs (32 vs 64) -> fits 128 VGPR -> 2 blocks/CU = 16 waves/CU (2x latency hiding).
// Weff_b[k][j] = Wbc[k][j] + tgt[k]*Wd[k][j]  (built once per block into registers, bf16)
// h_pre[l][j]  = U[j] + item[l] @ Weff_b      (K=128 bf16 MFMA; U folded into acc init)
// score[l]     = relu(h_pre[l]) @ W2 + b2;  out[b][d] = sum_{l<slen} score[l]*item[l][d]
// Pipeline: ONE barrier per tile, 1-deep prefetch (2-deep proven neutral in R2).
// Hazards: in window (sync_mt, sync_{mt+1}) writes = Xl[(mt+1)&3], scoreP[mt&1];
// reads = Xl[mt&3], Xl[(mt-1)&3], scoreP[(mt-1)&1] -- disjoint; >=2 barriers before reuse.
__launch_bounds__(512, 4)
__global__ void din_main(const float* __restrict__ target, const float* __restrict__ item_seq,
                         const int* __restrict__ seq_len, const float* __restrict__ W2,
                         const float* __restrict__ b2p, const short* __restrict__ Wbc,
                         const short* __restrict__ Wd, const float* __restrict__ U,
                         float* __restrict__ out) {
    const int b = blockIdx.x;
    const int tid = threadIdx.x;     // 0..511
    const int lane = tid & 63;
    const int w = tid >> 6;          // wave 0..7
    const int col = lane & 15;       // MFMA C col / B-frag n
    const int q = lane >> 4;         // quad

    const int slen = seq_len[b];
    const int nt = (slen + 15) >> 4;

    // Early-exit: no valid rows -> out is zero (uniform branch, before any barrier).
    if (nt == 0) {
        if (tid < 128) out[b * 128 + tid] = 0.f;
        return;
    }

    __shared__ __attribute__((aligned(16))) short Xl[4][16 * XS];   // quad buffer, 17.4 KB
    __shared__ __attribute__((aligned(16))) float scoreP[2][16][8]; // double buffer, 1 KB
    __shared__ __attribute__((aligned(16))) float outr[16][128];    // row partials, 8 KB

    // Staging/accum assignment: row r (0..15), col-quad cq (4 f32 / 4 bf16 elems)
    const int r = tid >> 5;
    const int cq = tid & 31;

    const float* item_b = item_seq + ((size_t)b * 200 + r) * 128 + cq * 4;

    // Prefetch tile 0 (rows 0..15 always in-bounds); 16B/thread
    float4 v0 = *(const float4*)item_b;

    const float b2 = b2p[0];

    // Per-lane epilogue constants straight from global (L2; 16-lane coalesced)
    float u_c[2], w2c[2];
#pragma unroll
    for (int i = 0; i < 2; i++) {
        int j = (w * 2 + i) * 16 + col;
        u_c[i] = U[b * 256 + j];
        w2c[i] = W2[j];
    }

    // ---- Build per-batch Weff B-fragments in registers: 2 n-tiles x 4 K-steps ----
    short8 bfrag[2][4];
    const float* tgt = target + b * 128;
#pragma unroll
    for (int s = 0; s < 4; s++) {
        const float4* tp = (const float4*)(tgt + s * 32 + q * 8);
        float4 ta = tp[0], tb = tp[1];
        float tk[8] = {ta.x, ta.y, ta.z, ta.w, tb.x, tb.y, tb.z, tb.w};
#pragma unroll
        for (int i = 0; i < 2; i++) {
            size_t off = ((size_t)((w * 2 + i) * 4 + s) * 64 + lane) * 8;
            short8 bc = *(const short8*)(Wbc + off);
            short8 dd = *(const short8*)(Wd + off);
            float f0 = fmaf(tk[0], bf2f(dd[0]), bf2f(bc[0]));
            float f1 = fmaf(tk[1], bf2f(dd[1]), bf2f(bc[1]));
            float f2 = fmaf(tk[2], bf2f(dd[2]), bf2f(bc[2]));
            float f3 = fmaf(tk[3], bf2f(dd[3]), bf2f(bc[3]));
            float f4 = fmaf(tk[4], bf2f(dd[4]), bf2f(bc[4]));
            float f5 = fmaf(tk[5], bf2f(dd[5]), bf2f(bc[5]));
            float f6 = fmaf(tk[6], bf2f(dd[6]), bf2f(bc[6]));
            float f7 = fmaf(tk[7], bf2f(dd[7]), bf2f(bc[7]));
            uint4 pe;
            pe.x = cvtpk(f0, f1);
            pe.y = cvtpk(f2, f3);
            pe.z = cvtpk(f4, f5);
            pe.w = cvtpk(f6, f7);
            bfrag[i][s] = *(short8*)&pe;
        }
    }

    f32x4 ov = (f32x4){0.f, 0.f, 0.f, 0.f};

    // Deferred score*item accumulation for tile pt: 1 row (r) x 4 cols (4*cq) per thread.
    // One uint2 LDS read + one broadcast 32B scoreP row read.
    auto accum_tile = [&](int pt) {
        const short* xp = Xl[pt & 3];
        const float4* sp4 = (const float4*)&scoreP[pt & 1][r][0];
        float4 sa = sp4[0], sb = sp4[1];
        float s = ((sa.x + sa.y) + (sa.z + sa.w)) + ((sb.x + sb.y) + (sb.z + sb.w)) + b2;
        s = (pt * 16 + r < slen) ? s : 0.f;
        uint2 xv = *(const uint2*)(xp + r * XS + 4 * cq);   // byte off = 272r+8cq, 8B-aligned
        ov[0] = fmaf(s, __uint_as_float(xv.x << 16), ov[0]);
        ov[1] = fmaf(s, __uint_as_float(xv.x & 0xffff0000u), ov[1]);
        ov[2] = fmaf(s, __uint_as_float(xv.y << 16), ov[2]);
        ov[3] = fmaf(s, __uint_as_float(xv.y & 0xffff0000u), ov[3]);
    };

    for (int mt = 0; mt < nt; ++mt) {
        short* xb = Xl[mt & 3];

        // Pack prefetched item row-chunk -> bf16 LDS (HW packed cvt); 8B/thread
        {
            uint2 pk;
            pk.x = cvtpk(v0.x, v0.y);
            pk.y = cvtpk(v0.z, v0.w);
            *(uint2*)(xb + r * XS + 4 * cq) = pk;
        }
        __syncthreads();   // the ONE barrier per tile: Xl[cur] visible, prev readers drained

        // Prefetch next tile (overlaps MFMA + epilogue + deferred accum)
        if (mt + 1 < nt) {
            int lr = (mt + 1) * 16 + r;
            if (lr > 199) lr = 199;   // clamp: masked out later, stays in-bounds
            v0 = *(const float4*)(item_b + ((size_t)(lr - r)) * 128);
        }

        // MFMA with U folded into accumulator init (u is col-indexed -> lane-constant)
        f32x4 acc0 = (f32x4){u_c[0], u_c[0], u_c[0], u_c[0]};
        f32x4 acc1 = (f32x4){u_c[1], u_c[1], u_c[1], u_c[1]};
        const short* arow = xb + col * XS + q * 8;
#pragma unroll
        for (int s = 0; s < 4; s++) {
            short8 af = *(const short8*)(arow + s * 32);
            acc0 = __builtin_amdgcn_mfma_f32_16x16x32_bf16(af, bfrag[0][s], acc0, 0, 0, 0);
            acc1 = __builtin_amdgcn_mfma_f32_16x16x32_bf16(af, bfrag[1][s], acc1, 0, 0, 0);
        }

        // Epilogue: relu + W2 partial over this wave's 32 cols; reduce 16 lanes
        float sv[4];
#pragma unroll
        for (int rg = 0; rg < 4; rg++) {
            float h0 = acc0[rg] > 0.f ? acc0[rg] : 0.f;
            float h1 = acc1[rg] > 0.f ? acc1[rg] : 0.f;
            sv[rg] = fmaf(h0, w2c[0], h1 * w2c[1]);
        }
#pragma unroll
        for (int off = 1; off < 16; off <<= 1) {
#pragma unroll
            for (int rg = 0; rg < 4; rg++) sv[rg] += __shfl_xor(sv[rg], off, 64);
        }
        if (col == 0) {
#pragma unroll
            for (int rg = 0; rg < 4; rg++) scoreP[mt & 1][q * 4 + rg][w] = sv[rg];
        }

        // Deferred accumulation of the PREVIOUS tile (scoreP[(mt-1)&1] visible since sync_mt)
        if (mt > 0) accum_tile(mt - 1);
    }

    // Drain: last tile's scores need one more barrier for visibility
    __syncthreads();
    accum_tile(nt - 1);

    // Final 16-way row-group reduction (once per kernel)
    *(float4*)&outr[r][4 * cq] = *(float4*)&ov;
    __syncthreads();
    if (tid < 128) {
        float s = 0.f;
#pragma unroll
        for (int k = 0; k < 16; k++) s += outr[k][tid];
        out[b * 128 + tid] = s;
    }
}

extern "C" void kernel_launch(void* const* d_in, const int* in_sizes, int n_in,
                              void* d_out, int out_size, void* d_ws, size_t ws_size,
                              hipStream_t stream) {
    const float* target   = (const float*)d_in[0];
    const float* item_seq = (const float*)d_in[1];
    const int*   seq_len  = (const int*)d_in[2];
    const float* W1       = (const float*)d_in[3];
    const float* b1       = (const float*)d_in[4];
    const float* W2       = (const float*)d_in[5];
    const float* b2       = (const float*)d_in[6];
    float* out = (float*)d_out;

    char* ws = (char*)d_ws;
    short* Wbc = (short*)ws;                    // 32768*2 = 65536 B
    short* Wd  = (short*)(ws + 65536);          // 65536 B
    float* U   = (float*)(ws + 131072);         // 2048*256*4 = 2 MB

    precompute<<<512, 256, 0, stream>>>(W1, b1, target, Wbc, Wd, U);
    din_main<<<2048, 512, 0, stream>>>(target, item_seq, seq_len, W2, b2, Wbc, Wd, U, out);
}

// Round 5
// 297.971 us; speedup vs baseline: 1.0439x; 1.0439x over previous
//
#include <hip/hip_runtime.h>
#include <hip/hip_bf16.h>

typedef short short8 __attribute__((ext_vector_type(8)));
typedef float f32x4 __attribute__((ext_vector_type(4)));

#define XS 136  // Xl row stride in bf16 elems: 128 + 8 pad (272 B/row -> 4-bank rotation)

static __device__ inline short f2bf(float f) {
    unsigned u = __float_as_uint(f);
    unsigned r = (u + 0x7fffu + ((u >> 16) & 1u)) >> 16;
    return (short)r;
}
static __device__ inline float bf2f(short s) {
    return __uint_as_float(((unsigned)(unsigned short)s) << 16);
}
// HW packed f32->bf16 RTNE (identical rounding to f2bf), 1 inst per 2 converts
static __device__ inline unsigned cvtpk(float lo, float hi) {
    unsigned r;
    asm("v_cvt_pk_bf16_f32 %0, %1, %2" : "=v"(r) : "v"(lo), "v"(hi));
    return r;
}

// Fused precompute.
// blocks [0,256):  U[b][j] = b1[j] + sum_d target[b][d] * (W1a[d][j] - W1c[d][j]) ; 8 b-rows/block
// blocks [256,512): build 128x256 bf16 fragment arrays in MFMA B-layout (16x16x32):
//   Wbc[k][n] = W1b[k][n] + W1c[k][n]   (item coefficient)
//   Wd [k][n] = W1d[k][n]               (dot coefficient, combined per-b in din_main)
// frag[((t*4+s)*64+l)*8+j] = src[s*32 + (l>>4)*8 + j][t*16 + (l&15)]
__global__ void precompute(const float* __restrict__ W1, const float* __restrict__ b1,
                           const float* __restrict__ target, short* __restrict__ Wbc,
                           short* __restrict__ Wd, float* __restrict__ U) {
    __shared__ float tl[1024];
    const int tid = threadIdx.x;
    if (blockIdx.x >= 256) {
        int idx = (blockIdx.x - 256) * 256 + tid;   // 65536 threads
        int half = idx >> 15;
        int i = idx & 32767;
        int j = i & 7;
        int l = (i >> 3) & 63;
        int s = (i >> 9) & 3;
        int t = i >> 11;
        int k = s * 32 + ((l >> 4) << 3) + j;
        int n = t * 16 + (l & 15);
        if (half == 0) Wbc[i] = f2bf(W1[(128 + k) * 256 + n] + W1[(256 + k) * 256 + n]);
        else           Wd[i]  = f2bf(W1[(384 + k) * 256 + n]);
        return;
    }
    const int b8 = blockIdx.x;
#pragma unroll
    for (int k = 0; k < 4; k++) tl[k * 256 + tid] = target[b8 * 1024 + k * 256 + tid];
    __syncthreads();
    float acc[8] = {0.f, 0.f, 0.f, 0.f, 0.f, 0.f, 0.f, 0.f};
#pragma unroll 8
    for (int d = 0; d < 128; ++d) {
        float wud = W1[d * 256 + tid] - W1[(256 + d) * 256 + tid];
#pragma unroll
        for (int r = 0; r < 8; r++) acc[r] += tl[r * 128 + d] * wud;
    }
    float bj = b1[tid];
#pragma unroll
    for (int r = 0; r < 8; r++) U[(b8 * 8 + r) * 256 + tid] = acc[r] + bj;
}

// Main fused kernel: one block per batch b; 4 waves; wave w owns n-tiles w*4..w*4+3.
// Weff_b[k][j] = Wbc[k][j] + tgt[k]*Wd[k][j]  (built once per block into registers, bf16)
// h_pre[l][j]  = U[j] + item[l] @ Weff_b      (K=128 bf16 MFMA; U folded into acc init)
// score[l]     = relu(h_pre[l]) @ W2 + b2;  out[b][d] = sum_{l<slen} score[l]*item[l][d]
// R5 = exact revert to R3 (best measured 298.3 us):
//   - 4 waves/block (R4's 8-wave split regressed +12.7us: duplicated A-frag LDS reads,
//     costlier 8-wave barrier, worse per-wave VALU:MFMA ratio)
//   - 1-deep prefetch (R2's 2-deep was neutral: 2 blocks/CU already hide it)
//   - accum remap: thread=(qd,gg) reads 2 rows x 4 cols per tile via uint2,
//     8-way row-group reduction once at kernel end via outr[8][128]
//   - direct L2 reads for target/U/W2 (no staging barrier); nt==0 early-exit
// Hazards: in window (sync_mt, sync_{mt+1}) writes = Xl[(mt+1)&3], scoreP[mt&1];
// reads = Xl[mt&3], Xl[(mt-1)&3], scoreP[(mt-1)&1] -- disjoint; >=2 barriers before reuse.
// NOTE (prior session): don't force min-waves >=3 — VGPR cap would spill bfrag.
__launch_bounds__(256, 2)
__global__ void din_main(const float* __restrict__ target, const float* __restrict__ item_seq,
                         const int* __restrict__ seq_len, const float* __restrict__ W2,
                         const float* __restrict__ b2p, const short* __restrict__ Wbc,
                         const short* __restrict__ Wd, const float* __restrict__ U,
                         float* __restrict__ out) {
    const int b = blockIdx.x;
    const int tid = threadIdx.x;
    const int lane = tid & 63;
    const int w = tid >> 6;      // wave 0..3
    const int col = lane & 15;   // MFMA C col / B-frag n
    const int q = lane >> 4;     // quad

    const int slen = seq_len[b];
    const int nt = (slen + 15) >> 4;

    // Early-exit: no valid rows -> out is zero; skip the whole setup (uniform branch,
    // no barrier has been executed yet).
    if (nt == 0) {
        if (tid < 128) out[b * 128 + tid] = 0.f;
        return;
    }

    __shared__ __attribute__((aligned(16))) short Xl[4][16 * XS];  // quad buffer, 17.4 KB
    __shared__ __attribute__((aligned(16))) float scoreP[2][16][4]; // double buffer
    __shared__ __attribute__((aligned(16))) float outr[8][128];     // row-group partials, 4 KB

    // Staging assignment: row r (0..15), 8 cols at c
    const int r = tid >> 4;
    const int c = (tid & 15) << 3;

    const float* item_b = item_seq + ((size_t)b * 200 + r) * 128 + c;

    // Prefetch tile 0 (rows 0..15 always in-bounds)
    float4 v0, v1;
    {
        const float4* src = (const float4*)item_b;
        v0 = src[0]; v1 = src[1];
    }

    const float b2 = b2p[0];

    // Per-lane epilogue constants straight from global (L2; 16-lane coalesced)
    float u_c[4], w2c[4];
#pragma unroll
    for (int i = 0; i < 4; i++) {
        int j = (w * 4 + i) * 16 + col;
        u_c[i] = U[b * 256 + j];
        w2c[i] = W2[j];
    }

    // ---- Build per-batch Weff B-fragments in registers: 4 n-tiles x 4 K-steps ----
    // target read directly (broadcast within 16-lane groups, L2/L3-resident)
    short8 bfrag[4][4];
    const float* tgt = target + b * 128;
#pragma unroll
    for (int s = 0; s < 4; s++) {
        const float4* tp = (const float4*)(tgt + s * 32 + q * 8);
        float4 ta = tp[0], tb = tp[1];
        float tk[8] = {ta.x, ta.y, ta.z, ta.w, tb.x, tb.y, tb.z, tb.w};
#pragma unroll
        for (int i = 0; i < 4; i++) {
            size_t off = ((size_t)((w * 4 + i) * 4 + s) * 64 + lane) * 8;
            short8 bc = *(const short8*)(Wbc + off);
            short8 dd = *(const short8*)(Wd + off);
            float f0 = fmaf(tk[0], bf2f(dd[0]), bf2f(bc[0]));
            float f1 = fmaf(tk[1], bf2f(dd[1]), bf2f(bc[1]));
            float f2 = fmaf(tk[2], bf2f(dd[2]), bf2f(bc[2]));
            float f3 = fmaf(tk[3], bf2f(dd[3]), bf2f(bc[3]));
            float f4 = fmaf(tk[4], bf2f(dd[4]), bf2f(bc[4]));
            float f5 = fmaf(tk[5], bf2f(dd[5]), bf2f(bc[5]));
            float f6 = fmaf(tk[6], bf2f(dd[6]), bf2f(bc[6]));
            float f7 = fmaf(tk[7], bf2f(dd[7]), bf2f(bc[7]));
            uint4 pe;
            pe.x = cvtpk(f0, f1);
            pe.y = cvtpk(f2, f3);
            pe.z = cvtpk(f4, f5);
            pe.w = cvtpk(f6, f7);
            bfrag[i][s] = *(short8*)&pe;
        }
    }

    // Accum assignment: col quad qd (4 cols at 4*qd), row group gg (rows 2gg, 2gg+1)
    const int qd = tid & 31;
    const int gg = tid >> 5;
    f32x4 ov = (f32x4){0.f, 0.f, 0.f, 0.f};

    // Deferred score*item accumulation for tile pt (uses Xl[pt&3], scoreP[pt&1]).
    // Per row: one uint2 LDS read (4 bf16) + one broadcast float4 scoreP read.
    auto accum_tile = [&](int pt) {
        const short* xp = Xl[pt & 3];
        const int l0p = pt * 16;
#pragma unroll
        for (int rr = 0; rr < 2; rr++) {
            int m = gg * 2 + rr;
            float4 sp = *(const float4*)&scoreP[pt & 1][m][0];
            float s = (sp.x + sp.y) + (sp.z + sp.w) + b2;
            s = (l0p + m < slen) ? s : 0.f;
            uint2 xv = *(const uint2*)(xp + m * XS + 4 * qd);   // byte off = 272m+8qd, 8B-aligned
            float x0 = __uint_as_float(xv.x << 16);
            float x1 = __uint_as_float(xv.x & 0xffff0000u);
            float x2 = __uint_as_float(xv.y << 16);
            float x3 = __uint_as_float(xv.y & 0xffff0000u);
            ov[0] = fmaf(s, x0, ov[0]);
            ov[1] = fmaf(s, x1, ov[1]);
            ov[2] = fmaf(s, x2, ov[2]);
            ov[3] = fmaf(s, x3, ov[3]);
        }
    };

    for (int mt = 0; mt < nt; ++mt) {
        short* xb = Xl[mt & 3];

        // Pack prefetched item rows -> bf16 LDS (HW packed cvt)
        {
            uint4 pk;
            pk.x = cvtpk(v0.x, v0.y);
            pk.y = cvtpk(v0.z, v0.w);
            pk.z = cvtpk(v1.x, v1.y);
            pk.w = cvtpk(v1.z, v1.w);
            *(uint4*)(xb + r * XS + c) = pk;
        }
        __syncthreads();   // the ONE barrier per tile: Xl[cur] visible, prev readers drained

        // Prefetch next tile (overlaps MFMA + epilogue + deferred accum)
        if (mt + 1 < nt) {
            int lr = (mt + 1) * 16 + r;
            if (lr > 199) lr = 199;   // clamp: masked out later, stays in-bounds
            const float4* src = (const float4*)(item_b + ((size_t)(lr - r)) * 128);
            v0 = src[0]; v1 = src[1];
        }

        // MFMA with U folded into accumulator init (u is col-indexed -> lane-constant)
        f32x4 acc[4];
#pragma unroll
        for (int i = 0; i < 4; i++) acc[i] = (f32x4){u_c[i], u_c[i], u_c[i], u_c[i]};
        const short* arow = xb + col * XS + q * 8;
#pragma unroll
        for (int s = 0; s < 4; s++) {
            short8 af = *(const short8*)(arow + s * 32);
#pragma unroll
            for (int i = 0; i < 4; i++)
                acc[i] = __builtin_amdgcn_mfma_f32_16x16x32_bf16(af, bfrag[i][s], acc[i], 0, 0, 0);
        }

        // Epilogue: relu + W2 partial over this wave's 64 cols; reduce 16 lanes
        float sv[4];
#pragma unroll
        for (int rg = 0; rg < 4; rg++) {
            float s0 = 0.f;
#pragma unroll
            for (int i = 0; i < 4; i++) {
                float h = acc[i][rg];
                h = h > 0.f ? h : 0.f;
                s0 = fmaf(h, w2c[i], s0);
            }
            sv[rg] = s0;
        }
#pragma unroll
        for (int off = 1; off < 16; off <<= 1) {
#pragma unroll
            for (int rg = 0; rg < 4; rg++) sv[rg] += __shfl_xor(sv[rg], off, 64);
        }
        if (col == 0) {
#pragma unroll
            for (int rg = 0; rg < 4; rg++) scoreP[mt & 1][q * 4 + rg][w] = sv[rg];
        }

        // Deferred accumulation of the PREVIOUS tile (scoreP[(mt-1)&1] visible since sync_mt)
        if (mt > 0) accum_tile(mt - 1);
    }

    // Drain: last tile's scores need one more barrier for visibility
    __syncthreads();
    accum_tile(nt - 1);

    // Final 8-way row-group reduction (once per kernel)
    *(float4*)&outr[gg][4 * qd] = *(float4*)&ov;
    __syncthreads();
    if (tid < 128) {
        float s = 0.f;
#pragma unroll
        for (int k = 0; k < 8; k++) s += outr[k][tid];
        out[b * 128 + tid] = s;
    }
}

extern "C" void kernel_launch(void* const* d_in, const int* in_sizes, int n_in,
                              void* d_out, int out_size, void* d_ws, size_t ws_size,
                              hipStream_t stream) {
    const float* target   = (const float*)d_in[0];
    const float* item_seq = (const float*)d_in[1];
    const int*   seq_len  = (const int*)d_in[2];
    const float* W1       = (const float*)d_in[3];
    const float* b1       = (const float*)d_in[4];
    const float* W2       = (const float*)d_in[5];
    const float* b2       = (const float*)d_in[6];
    float* out = (float*)d_out;

    char* ws = (char*)d_ws;
    short* Wbc = (short*)ws;                    // 32768*2 = 65536 B
    short* Wd  = (short*)(ws + 65536);          // 65536 B
    float* U   = (float*)(ws + 131072);         // 2048*256*4 = 2 MB

    precompute<<<512, 256, 0, stream>>>(W1, b1, target, Wbc, Wd, U);
    din_main<<<2048, 256, 0, stream>>>(target, item_seq, seq_len, W2, b2, Wbc, Wd, U, out);
}